// Round 1
// 109.923 us; speedup vs baseline: 1.0837x; 1.0837x over previous
//
#include <hip/hip_runtime.h>
#include <hip/hip_bf16.h>

// loss = (100/N^2) * [3*s_tt + s_rr + s_dd + s_ii - 2*(s_tr + s_td + s_ti)]
// where s_ab = || n_a^T n_b ||_F^2   (n_x = row-normalized input, N=4096, D=512)
//
// fp8 pipeline, 2 dispatches:
// K1 preprocess: fused rownorm + scale(16/||r||) + fp8 cast + transpose
//                -> nT8[mod][c][k] (8 MB, K-contiguous); also zeroes d_out.
//                32-row strips (grid 128x4 = 512 blocks, 2/CU). Transpose is
//                done per-thread on 4x4 register blocks: scale -> bf16 round
//                (bit-identical to previous pipeline) -> fp8 pack -> ONE
//                ds_write_b32 per column (vs 4x ds_write_b16 before); the
//                output phase is a pure LDS->global 16B copy.
// K2 gram:       TN-GEMMs 512x512 fp8, 64x64 tiles, full K per block
//                (Frobenius is local per tile), K-chunk 128, dbuf 32 KB LDS,
//                XOR swizzle, b128 conflict-free frag reads, local Frobenius
//                -> 1 atomic/block. SELF products (t,t),(r,r),(d,d),(i,i) are
//                symmetric => only tiles i<=j are computed, off-diag weighted
//                x2: 4*36 + 3*64 = 336 blocks (was 448; -25% FLOPs+traffic).
// Frobenius structure => immune to any consistent K-permutation and to the
// MFMA C/D layout; x16 pre-scale folded into normalization, /16^4 at the end.

typedef __attribute__((ext_vector_type(4))) float floatx4;
typedef __attribute__((ext_vector_type(2))) long long llx2;

#define N_ROWS 4096
#define DDIM   512
// 100 / (4096^2 * 16^4)
#define LOSS_SCALE 9.094947017729282e-11f

__device__ __forceinline__ const float* sel_mod(int mod, const float* a,
                                                const float* b, const float* c,
                                                const float* d) {
  return mod == 0 ? a : mod == 1 ? b : mod == 2 ? c : d;
}

// bf16 RNE round-trip (keeps nT8 bit-identical to the bf16-intermediate path)
__device__ __forceinline__ float bfr(float x) {
  __hip_bfloat16 h = __float2bfloat16(x);
  unsigned short u = *(unsigned short*)&h;
  return __uint_as_float(((unsigned int)u) << 16);
}

__global__ __launch_bounds__(256) void preprocess_kernel(
    const float* __restrict__ in0, const float* __restrict__ in1,
    const float* __restrict__ in2, const float* __restrict__ in3,
    unsigned char* __restrict__ nT8, float* __restrict__ out) {
  // grid: x = 128 (k-strips of 32 rows), y = 4 (mod). 256 threads = 4 waves.
  int mod = blockIdx.y;
  int k0 = blockIdx.x * 32;
  const float* X = sel_mod(mod, in0, in1, in2, in3) + (size_t)k0 * DDIM;

  if (blockIdx.x == 0 && blockIdx.y == 0 && threadIdx.x == 0)
    out[0] = 0.f;  // d_out re-poisoned each call; gram (next dispatch) accums

  __shared__ float rsc[32];
  // fp8-packed transpose tile: [128 cols][8 words of 4 k-bytes], stride 9
  // (odd stride => 8 distinct banks on the strided writes, ~4-way conflict)
  __shared__ unsigned int t8[128 * 9];

  int t = threadIdx.x;
  int w = t >> 6, lane = t & 63;

  // phase A: row norms for this strip (8 rows per wave)
#pragma unroll
  for (int i = 0; i < 8; ++i) {
    int r = w * 8 + i;
    const float4* rp = (const float4*)(X + (size_t)r * DDIM);
    float4 a = rp[lane];
    float4 b = rp[lane + 64];
    float ss = a.x * a.x + a.y * a.y + a.z * a.z + a.w * a.w +
               b.x * b.x + b.y * b.y + b.z * b.z + b.w * b.w;
#pragma unroll
    for (int off = 32; off > 0; off >>= 1) ss += __shfl_down(ss, off, 64);
    if (lane == 0) rsc[r] = 16.0f / fmaxf(sqrtf(ss), 1e-12f);  // x16 folded
  }
  __syncthreads();

  int ag = t >> 5;  // row-group 0..7  (rows 4*ag .. 4*ag+3)
  int bg = t & 31;  // col-group 0..31 (cols 4*bg .. 4*bg+3 within panel)
  float sc[4];
#pragma unroll
  for (int q = 0; q < 4; ++q) sc[q] = rsc[ag * 4 + q];

  // 4 panels of 128 cols; rows re-read from L2 (strip stays hot)
  for (int p = 0; p < 4; ++p) {
    // phase B: 4x4 fp32 register block -> scale -> bf16 round -> fp8 pack
    float4 v[4];
#pragma unroll
    for (int q = 0; q < 4; ++q)
      v[q] = ((const float4*)(X + (size_t)(ag * 4 + q) * DDIM + p * 128))[bg];
#pragma unroll
    for (int j = 0; j < 4; ++j) {
      float f0 = bfr(((const float*)&v[0])[j] * sc[0]);
      float f1 = bfr(((const float*)&v[1])[j] * sc[1]);
      float f2 = bfr(((const float*)&v[2])[j] * sc[2]);
      float f3 = bfr(((const float*)&v[3])[j] * sc[3]);
      unsigned int pk = __builtin_amdgcn_cvt_pk_fp8_f32(f0, f1, 0, 0);
      pk = __builtin_amdgcn_cvt_pk_fp8_f32(f2, f3, pk, 1);  // k-order bytes
      t8[(bg * 4 + j) * 9 + ag] = pk;
    }
    __syncthreads();
    // phase C: pure copy LDS -> global, 16B (16 k-values) per thread
    {
      int col = t >> 1, g = t & 1;
      uint4 o;
      o.x = t8[col * 9 + g * 4 + 0];
      o.y = t8[col * 9 + g * 4 + 1];
      o.z = t8[col * 9 + g * 4 + 2];
      o.w = t8[col * 9 + g * 4 + 3];
      *(uint4*)(nT8 + ((size_t)(mod * DDIM + p * 128 + col)) * N_ROWS + k0 +
                g * 16) = o;
    }
    __syncthreads();
  }
}

__device__ __forceinline__ void stage_tiles(
    const unsigned char* __restrict__ Abase,
    const unsigned char* __restrict__ Bbase, int k0,
    unsigned char* ls, int w, int lane) {
  // A: 64 local rows at ls[0..8191]; B: 64 local rows at ls[8192..16383].
  // 16B-chunk XOR swizzle on the GLOBAL side: LDS slot s of local row r holds
  // global chunk s ^ ((r>>1)&7); LDS side is the wave-uniform base + lane*16
  // required by global_load_lds.
  int rr = lane >> 3;          // row 0..7 within the 8-row staging group
  int s = lane & 7;            // 16B slot within 128B row
#pragma unroll
  for (int c = 0; c < 2; ++c) {
    int base = c * 32 + w * 8;  // wave-uniform; 2 x (4 waves x 8 rows) = 64
    int row = base + rr;
    int gc = s ^ ((row >> 1) & 7);
    const unsigned char* ga = Abase + (size_t)row * N_ROWS + k0 + gc * 16;
    __builtin_amdgcn_global_load_lds(
        (__attribute__((address_space(1))) void*)(void*)ga,
        (__attribute__((address_space(3))) void*)(void*)&ls[base * 128],
        16, 0, 0);
  }
#pragma unroll
  for (int c = 0; c < 2; ++c) {
    int base = c * 32 + w * 8;
    int row = base + rr;
    int gc = s ^ ((row >> 1) & 7);
    const unsigned char* gb = Bbase + (size_t)row * N_ROWS + k0 + gc * 16;
    __builtin_amdgcn_global_load_lds(
        (__attribute__((address_space(1))) void*)(void*)gb,
        (__attribute__((address_space(3))) void*)(void*)&ls[8192 + base * 128],
        16, 0, 0);
  }
}

__device__ __forceinline__ void compute_tiles(
    const unsigned char* ls, floatx4 acc[2][2], int wm, int wn, int lm,
    int lq) {
  // Lane lq's 4 K-steps live in LDS slots lq*2, lq*2+1 (after unswizzle):
  // two b128 reads per fragment row (conflict-free, uniform 2 lanes/bank).
  // (ks,lq) -> global K-unit lq*4 + (ks>>1)*2 + (ks&1): a uniform K-perm
  // applied identically to A and B => Frobenius-invariant.
  llx2 A16[2][2], B16[2][2];
#pragma unroll
  for (int mi = 0; mi < 2; ++mi) {
    int row = wm + mi * 16 + lm;            // local A row 0..63
    int sw = (row >> 1) & 7;
    A16[mi][0] = *(const llx2*)&ls[row * 128 + ((lq * 2) ^ sw) * 16];
    A16[mi][1] = *(const llx2*)&ls[row * 128 + ((lq * 2 + 1) ^ sw) * 16];
  }
#pragma unroll
  for (int ni = 0; ni < 2; ++ni) {
    int row = wn + ni * 16 + lm;            // local B row 0..63
    int sw = (row >> 1) & 7;
    B16[ni][0] = *(const llx2*)&ls[8192 + row * 128 + ((lq * 2) ^ sw) * 16];
    B16[ni][1] =
        *(const llx2*)&ls[8192 + row * 128 + ((lq * 2 + 1) ^ sw) * 16];
  }
#pragma unroll
  for (int ks = 0; ks < 4; ++ks) {
    int h = ks >> 1, e = ks & 1;
#pragma unroll
    for (int mi = 0; mi < 2; ++mi)
#pragma unroll
      for (int ni = 0; ni < 2; ++ni)
        acc[mi][ni] = __builtin_amdgcn_mfma_f32_16x16x32_fp8_fp8(
            A16[mi][h][e], B16[ni][h][e], acc[mi][ni], 0, 0, 0);
  }
}

__global__ __launch_bounds__(256) void gram_frob_kernel(
    const unsigned char* __restrict__ nT8, float* __restrict__ out) {
  // 336 blocks, flat decode:
  //   bx <  144: self product (mods {t,r,d,i} with weights {3,1,1,1}),
  //              triangular tile i<=j of the 8x8 tile grid; off-diag x2.
  //   bx >= 144: cross product (t,rgb)/(t,depth)/(t,ir), weight -2, full 8x8.
  __shared__ __align__(16) unsigned char ls[2][16384];  // dbuf, 32 KB total
  __shared__ float red[4];

  int bx = blockIdx.x;
  int pa_, pb_, ti, tj;
  float wgt;
  if (bx < 144) {
    int p = bx / 36;
    int t36 = bx - p * 36;
    int i = 0;
    while (t36 >= 8 - i) { t36 -= 8 - i; ++i; }  // row i has 8-i entries
    ti = i;
    tj = i + t36;
    const int   sm[4] = {3, 0, 1, 2};
    const float sw_[4] = {3.f, 1.f, 1.f, 1.f};
    pa_ = sm[p];
    pb_ = sm[p];
    wgt = sw_[p] * (ti == tj ? 1.f : 2.f);
  } else {
    int r = bx - 144;
    int p = r >> 6;            // 0..2 -> rgb, depth, ir
    int t64 = r & 63;
    ti = t64 >> 3;
    tj = t64 & 7;
    pa_ = 3;
    pb_ = p;
    wgt = -2.f;
  }

  int a0 = ti * 64;
  int b0 = tj * 64;
  const unsigned char* Abase = nT8 + ((size_t)pa_ * DDIM + a0) * N_ROWS;
  const unsigned char* Bbase = nT8 + ((size_t)pb_ * DDIM + b0) * N_ROWS;

  int t = threadIdx.x;
  int w = t >> 6;              // 4 waves: 2 (M) x 2 (N) sub-tiles of 32x32
  int lane = t & 63;
  int wm = (w >> 1) * 32;
  int wn = (w & 1) * 32;
  int lm = lane & 15;
  int lq = lane >> 4;

  floatx4 zero = {0.f, 0.f, 0.f, 0.f};
  floatx4 acc[2][2];
#pragma unroll
  for (int mi = 0; mi < 2; ++mi)
#pragma unroll
    for (int ni = 0; ni < 2; ++ni) acc[mi][ni] = zero;

  // 32 chunks of K=128, double-buffered (full K: Frobenius is tile-local)
  stage_tiles(Abase, Bbase, 0, ls[0], w, lane);
  __syncthreads();
  for (int i = 0; i < 15; ++i) {
    int k0 = (2 * i + 1) * 128;
    stage_tiles(Abase, Bbase, k0, ls[1], w, lane);
    compute_tiles(ls[0], acc, wm, wn, lm, lq);
    __syncthreads();
    stage_tiles(Abase, Bbase, k0 + 128, ls[0], w, lane);
    compute_tiles(ls[1], acc, wm, wn, lm, lq);
    __syncthreads();
  }
  stage_tiles(Abase, Bbase, 31 * 128, ls[1], w, lane);
  compute_tiles(ls[0], acc, wm, wn, lm, lq);  // chunk 30
  __syncthreads();
  compute_tiles(ls[1], acc, wm, wn, lm, lq);  // chunk 31

  // Local Frobenius: C/D layout is a bijection -> sum of squares is exact.
  float s = 0.f;
#pragma unroll
  for (int mi = 0; mi < 2; ++mi)
#pragma unroll
    for (int ni = 0; ni < 2; ++ni)
#pragma unroll
      for (int r = 0; r < 4; ++r) {
        float v = acc[mi][ni][r];
        s += v * v;
      }
#pragma unroll
  for (int off = 32; off > 0; off >>= 1) s += __shfl_down(s, off, 64);
  if (lane == 0) red[w] = s;
  __syncthreads();
  if (t == 0) {
    float tot = red[0] + red[1] + red[2] + red[3];
    atomicAdd(out, wgt * LOSS_SCALE * tot);  // 336 atomics total
  }
}

extern "C" void kernel_launch(void* const* d_in, const int* in_sizes, int n_in,
                              void* d_out, int out_size, void* d_ws, size_t ws_size,
                              hipStream_t stream) {
  const float* in_rgb   = (const float*)d_in[0];
  const float* in_depth = (const float*)d_in[1];
  const float* in_ir    = (const float*)d_in[2];
  const float* in_t     = (const float*)d_in[3];

  unsigned char* nT8 = (unsigned char*)d_ws;  // 8 MB fp8, K-contiguous

  preprocess_kernel<<<dim3(128, 4), 256, 0, stream>>>(
      in_rgb, in_depth, in_ir, in_t, nT8, (float*)d_out);
  gram_frob_kernel<<<dim3(336), 256, 0, stream>>>(nT8, (float*)d_out);
}

// Round 2
// 108.762 us; speedup vs baseline: 1.0953x; 1.0107x over previous
//
#include <hip/hip_runtime.h>
#include <hip/hip_bf16.h>

// loss = (100/N^2) * [3*s_tt + s_rr + s_dd + s_ii - 2*(s_tr + s_td + s_ti)]
// where s_ab = || n_a^T n_b ||_F^2   (n_x = row-normalized input, N=4096, D=512)
//
// fp8 pipeline, 2 dispatches:
// K1 preprocess: SINGLE-READ fused rownorm + scale(16/||r||) + fp8 cast +
//                transpose -> nT8[mod][c][k] (8 MB, K-contiguous); zeroes
//                d_out. 64-row strips, 256 blocks (1/CU), 512 threads. Each
//                thread keeps its 4 rows x 16 cols in registers (16 dwordx4),
//                row norms come from those registers via half-wave shfl
//                reduce (1 sync), then scale -> bf16 RNE -> fp8 pack ->
//                LDS transpose buffer -> 64B-contiguous column stores.
// K2 gram:       TN-GEMMs 512x512 fp8, one 64x64 tile per 64-thread block
//                (4x4 of 16x16x32, acc=64 VGPR) -- halves LDS read traffic
//                vs the 2x2-wave split (no fragment read twice). Single wave
//                => NO barriers: 4-buffer LDS (64 KB), 2-chunk-deep prefetch
//                with counted s_waitcnt vmcnt(32/16/0), XOR-swizzled stage,
//                b128 conflict-free frag reads, setprio around MFMA, local
//                Frobenius -> 1 atomic/block. SELF products are symmetric =>
//                only tiles i<=j, off-diag weighted x2: 4*36+3*64=336 blocks.
// Frobenius structure => immune to any consistent K-permutation and to the
// MFMA C/D layout; x16 pre-scale folded into normalization, /16^4 at the end.

typedef __attribute__((ext_vector_type(4))) float floatx4;
typedef __attribute__((ext_vector_type(2))) long long llx2;

#define N_ROWS 4096
#define DDIM   512
// 100 / (4096^2 * 16^4)
#define LOSS_SCALE 9.094947017729282e-11f

__device__ __forceinline__ const float* sel_mod(int mod, const float* a,
                                                const float* b, const float* c,
                                                const float* d) {
  return mod == 0 ? a : mod == 1 ? b : mod == 2 ? c : d;
}

// bf16 RNE round-trip (keeps nT8 numerics identical to the bf16 pipeline)
__device__ __forceinline__ float bfr(float x) {
  __hip_bfloat16 h = __float2bfloat16(x);
  unsigned short u = *(unsigned short*)&h;
  return __uint_as_float(((unsigned int)u) << 16);
}

__global__ __launch_bounds__(512) void preprocess_kernel(
    const float* __restrict__ in0, const float* __restrict__ in1,
    const float* __restrict__ in2, const float* __restrict__ in3,
    unsigned char* __restrict__ nT8, float* __restrict__ out) {
  // grid: x = 64 (k-strips of 64 rows), y = 4 (mod). 512 threads = 8 waves.
  int mod = blockIdx.y;
  int k0 = blockIdx.x * 64;
  const float* X = sel_mod(mod, in0, in1, in2, in3) + (size_t)k0 * DDIM;

  if (blockIdx.x == 0 && blockIdx.y == 0 && threadIdx.x == 0)
    out[0] = 0.f;  // d_out re-poisoned each call; gram (next dispatch) accums

  __shared__ float rsc[64];
  // fp8-packed transpose tile: [512 cols][16 row-groups + 1 pad] words.
  // stride 17 (odd): pack-writes ~8 banks, phase-C b32 reads ~2-way (free).
  __shared__ unsigned int t8[512 * 17];  // 34.8 KB

  int t = threadIdx.x;
  int a = t >> 5;   // row-group 0..15 -> rows 4a..4a+3
  int bg = t & 31;  // col-group: float4 bg within each 128-col panel

  // single global read: 4 rows x 4 panels of float4 -> 64 VGPRs
  float4 v[4][4];  // [q][p]
#pragma unroll
  for (int q = 0; q < 4; ++q)
#pragma unroll
    for (int p = 0; p < 4; ++p)
      v[q][p] = ((const float4*)(X + (size_t)(4 * a + q) * DDIM + p * 128))[bg];

  // row-norm partials from registers; rows of group a live in one 32-lane
  // half-wave (t = a*32 + bg) -> width-32 shfl reduce
  float ss[4];
#pragma unroll
  for (int q = 0; q < 4; ++q) {
    float acc = 0.f;
#pragma unroll
    for (int p = 0; p < 4; ++p) {
      float4 u = v[q][p];
      acc += u.x * u.x + u.y * u.y + u.z * u.z + u.w * u.w;
    }
    ss[q] = acc;
  }
#pragma unroll
  for (int off = 16; off > 0; off >>= 1)
#pragma unroll
    for (int q = 0; q < 4; ++q) ss[q] += __shfl_down(ss[q], off, 32);
  if (bg == 0) {
#pragma unroll
    for (int q = 0; q < 4; ++q)
      rsc[4 * a + q] = 16.0f / fmaxf(sqrtf(ss[q]), 1e-12f);  // x16 folded
  }
  __syncthreads();

  float sc[4];
#pragma unroll
  for (int q = 0; q < 4; ++q) sc[q] = rsc[4 * a + q];

  // scale -> bf16 round -> fp8 pack (4 k-rows per word), straight from regs
#pragma unroll
  for (int p = 0; p < 4; ++p)
#pragma unroll
    for (int j = 0; j < 4; ++j) {
      float f0 = bfr(((const float*)&v[0][p])[j] * sc[0]);
      float f1 = bfr(((const float*)&v[1][p])[j] * sc[1]);
      float f2 = bfr(((const float*)&v[2][p])[j] * sc[2]);
      float f3 = bfr(((const float*)&v[3][p])[j] * sc[3]);
      unsigned int pk = __builtin_amdgcn_cvt_pk_fp8_f32(f0, f1, 0, 0);
      pk = __builtin_amdgcn_cvt_pk_fp8_f32(f2, f3, pk, 1);  // k-order bytes
      t8[(p * 128 + bg * 4 + j) * 17 + a] = pk;
    }
  __syncthreads();

  // output: 2048 x 16B; 4 adjacent lanes share a col -> 64B-contiguous runs
#pragma unroll
  for (int it = 0; it < 4; ++it) {
    int idx = it * 512 + t;
    int col = idx >> 2;  // 0..511
    int g = idx & 3;     // 16-byte k-group within the 64-row strip
    uint4 o;
    o.x = t8[col * 17 + g * 4 + 0];
    o.y = t8[col * 17 + g * 4 + 1];
    o.z = t8[col * 17 + g * 4 + 2];
    o.w = t8[col * 17 + g * 4 + 3];
    *(uint4*)(nT8 + ((size_t)(mod * DDIM + col)) * N_ROWS + k0 + g * 16) = o;
  }
}

__device__ __forceinline__ void stage_tiles1w(
    const unsigned char* __restrict__ Abase,
    const unsigned char* __restrict__ Bbase, int k0,
    unsigned char* ls, int lane) {
  // One wave stages A: 64 rows -> ls[0..8191], B: 64 rows -> ls[8192..16383].
  // 16B-chunk XOR swizzle on the GLOBAL side: LDS slot s of local row r holds
  // global chunk s ^ ((r>>1)&7); LDS side is the wave-uniform base + lane*16
  // required by global_load_lds.
  int rr = lane >> 3;  // row 0..7 within the 8-row staging group
  int s = lane & 7;    // 16B slot within 128B row
#pragma unroll
  for (int c = 0; c < 8; ++c) {
    int row = c * 8 + rr;
    int gc = s ^ ((row >> 1) & 7);
    const unsigned char* ga = Abase + (size_t)row * N_ROWS + k0 + gc * 16;
    __builtin_amdgcn_global_load_lds(
        (__attribute__((address_space(1))) void*)(void*)ga,
        (__attribute__((address_space(3))) void*)(void*)&ls[c * 1024],
        16, 0, 0);
  }
#pragma unroll
  for (int c = 0; c < 8; ++c) {
    int row = c * 8 + rr;
    int gc = s ^ ((row >> 1) & 7);
    const unsigned char* gb = Bbase + (size_t)row * N_ROWS + k0 + gc * 16;
    __builtin_amdgcn_global_load_lds(
        (__attribute__((address_space(1))) void*)(void*)gb,
        (__attribute__((address_space(3))) void*)(void*)&ls[8192 + c * 1024],
        16, 0, 0);
  }
}

__device__ __forceinline__ void compute_tiles1w(const unsigned char* ls,
                                                floatx4 acc[4][4], int lm,
                                                int lq) {
  // Lane lq's 4 K-steps live in LDS slots lq*2, lq*2+1 (after unswizzle):
  // two b128 reads per fragment row (conflict-free, uniform 2 lanes/bank).
  // (ks,lq) -> global K-unit lq*4 + (ks>>1)*2 + (ks&1): a uniform K-perm
  // applied identically to A and B => Frobenius-invariant.
  llx2 A16[4][2], B16[4][2];
#pragma unroll
  for (int mi = 0; mi < 4; ++mi) {
    int row = mi * 16 + lm;  // local A row 0..63
    int sw = (row >> 1) & 7;
    A16[mi][0] = *(const llx2*)&ls[row * 128 + ((lq * 2) ^ sw) * 16];
    A16[mi][1] = *(const llx2*)&ls[row * 128 + ((lq * 2 + 1) ^ sw) * 16];
  }
#pragma unroll
  for (int ni = 0; ni < 4; ++ni) {
    int row = ni * 16 + lm;  // local B row 0..63
    int sw = (row >> 1) & 7;
    B16[ni][0] = *(const llx2*)&ls[8192 + row * 128 + ((lq * 2) ^ sw) * 16];
    B16[ni][1] =
        *(const llx2*)&ls[8192 + row * 128 + ((lq * 2 + 1) ^ sw) * 16];
  }
  __builtin_amdgcn_s_setprio(1);
#pragma unroll
  for (int ks = 0; ks < 4; ++ks) {
    int h = ks >> 1, e = ks & 1;
#pragma unroll
    for (int mi = 0; mi < 4; ++mi)
#pragma unroll
      for (int ni = 0; ni < 4; ++ni)
        acc[mi][ni] = __builtin_amdgcn_mfma_f32_16x16x32_fp8_fp8(
            A16[mi][h][e], B16[ni][h][e], acc[mi][ni], 0, 0, 0);
  }
  __builtin_amdgcn_s_setprio(0);
}

__global__ __launch_bounds__(64) void gram_frob_kernel(
    const unsigned char* __restrict__ nT8, float* __restrict__ out) {
  // 336 single-wave blocks, flat decode:
  //   bx <  144: self product (mods {t,r,d,i} with weights {3,1,1,1}),
  //              triangular tile i<=j of the 8x8 tile grid; off-diag x2.
  //   bx >= 144: cross product (t,rgb)/(t,depth)/(t,ir), weight -2, full 8x8.
  __shared__ __align__(16) unsigned char ls[4][16384];  // 4-deep, 64 KB

  int bx = blockIdx.x;
  int pa_, pb_, ti, tj;
  float wgt;
  if (bx < 144) {
    int p = bx / 36;
    int t36 = bx - p * 36;
    int i = 0;
    while (t36 >= 8 - i) { t36 -= 8 - i; ++i; }  // row i has 8-i entries
    ti = i;
    tj = i + t36;
    const int   sm[4] = {3, 0, 1, 2};
    const float sw_[4] = {3.f, 1.f, 1.f, 1.f};
    pa_ = sm[p];
    pb_ = sm[p];
    wgt = sw_[p] * (ti == tj ? 1.f : 2.f);
  } else {
    int r = bx - 144;
    int p = r >> 6;  // 0..2 -> rgb, depth, ir
    int t64 = r & 63;
    ti = t64 >> 3;
    tj = t64 & 7;
    pa_ = 3;
    pb_ = p;
    wgt = -2.f;
  }

  const unsigned char* Abase = nT8 + ((size_t)pa_ * DDIM + ti * 64) * N_ROWS;
  const unsigned char* Bbase = nT8 + ((size_t)pb_ * DDIM + tj * 64) * N_ROWS;

  int lane = threadIdx.x;  // one wave per block
  int lm = lane & 15;
  int lq = lane >> 4;

  floatx4 zero = {0.f, 0.f, 0.f, 0.f};
  floatx4 acc[4][4];
#pragma unroll
  for (int mi = 0; mi < 4; ++mi)
#pragma unroll
    for (int ni = 0; ni < 4; ++ni) acc[mi][ni] = zero;

  // 32 chunks of K=128; single wave => no barriers. 2-chunk-deep prefetch
  // with counted vmcnt: only global_load_lds ops count against vmcnt here.
  unsigned char* p0 = ls[0];
  unsigned char* p1 = ls[1];
  unsigned char* p2 = ls[2];
  unsigned char* p3 = ls[3];
  stage_tiles1w(Abase, Bbase, 0, p0, lane);
  stage_tiles1w(Abase, Bbase, 128, p1, lane);
  stage_tiles1w(Abase, Bbase, 256, p2, lane);
  for (int i = 0; i < 30; ++i) {
    // outstanding <= 48 (chunks i, i+1, i+2); drain to 32 => chunk i landed
    asm volatile("s_waitcnt vmcnt(32)" ::: "memory");
    __builtin_amdgcn_sched_barrier(0);
    if (i < 29)
      stage_tiles1w(Abase, Bbase, (i + 3) * 128, p3, lane);  // issue early
    compute_tiles1w(p0, acc, lm, lq);
    unsigned char* tmp = p0; p0 = p1; p1 = p2; p2 = p3; p3 = tmp;
  }
  asm volatile("s_waitcnt vmcnt(16)" ::: "memory");
  __builtin_amdgcn_sched_barrier(0);
  compute_tiles1w(p0, acc, lm, lq);  // chunk 30
  p0 = p1;
  asm volatile("s_waitcnt vmcnt(0)" ::: "memory");
  __builtin_amdgcn_sched_barrier(0);
  compute_tiles1w(p0, acc, lm, lq);  // chunk 31

  // Local Frobenius: C/D layout is a bijection -> sum of squares is exact.
  float s = 0.f;
#pragma unroll
  for (int mi = 0; mi < 4; ++mi)
#pragma unroll
    for (int ni = 0; ni < 4; ++ni)
#pragma unroll
      for (int r = 0; r < 4; ++r) {
        float v = acc[mi][ni][r];
        s += v * v;
      }
#pragma unroll
  for (int off = 32; off > 0; off >>= 1) s += __shfl_down(s, off, 64);
  if (lane == 0) atomicAdd(out, wgt * LOSS_SCALE * s);  // 336 atomics total
}

extern "C" void kernel_launch(void* const* d_in, const int* in_sizes, int n_in,
                              void* d_out, int out_size, void* d_ws, size_t ws_size,
                              hipStream_t stream) {
  const float* in_rgb   = (const float*)d_in[0];
  const float* in_depth = (const float*)d_in[1];
  const float* in_ir    = (const float*)d_in[2];
  const float* in_t     = (const float*)d_in[3];

  unsigned char* nT8 = (unsigned char*)d_ws;  // 8 MB fp8, K-contiguous

  preprocess_kernel<<<dim3(64, 4), 512, 0, stream>>>(
      in_rgb, in_depth, in_ir, in_t, nT8, (float*)d_out);
  gram_frob_kernel<<<dim3(336), 64, 0, stream>>>(nT8, (float*)d_out);
}

// Round 3
// 105.187 us; speedup vs baseline: 1.1325x; 1.0340x over previous
//
#include <hip/hip_runtime.h>
#include <hip/hip_bf16.h>

// loss = (100/N^2) * [3*s_tt + s_rr + s_dd + s_ii - 2*(s_tr + s_td + s_ti)]
// where s_ab = || n_a^T n_b ||_F^2   (n_x = row-normalized input, N=4096, D=512)
//
// fp8 pipeline, 2 dispatches:
// K1 preprocess: SINGLE-READ fused rownorm + scale(16/||r||) + fp8 cast +
//                transpose -> nT8[mod][c][k] (8 MB, K-contiguous); zeroes
//                d_out. 64-row strips, 256 blocks (1/CU), 512 threads,
//                register-resident 4x4 blocks, one global read of inputs.
// K2 gram:       TN-GEMMs 512x512 fp8 via MX-scaled
//                mfma_scale_f32_16x16x128_f8f6f4 with UNIT scales (0x7F):
//                identical fp8 dot product at 2.3x the non-scaled fp8 rate,
//                one instruction per K=128 chunk per 16x16 tile. 336 blocks
//                x 128 threads (2 waves, N-split 64x32 each). Staging split:
//                wave0 stages A, wave1 stages B; per-wave counted
//                s_waitcnt vmcnt(16/8/0) + raw s_barrier (no drain), 4-buf
//                LDS (64 KB), 3-deep prefetch, XOR-swizzled stage + b128
//                conflict-free frag reads. Bijective XCD swizzle (336=8*42)
//                keeps each XCD's panel working set (~3.3 MB) L2-resident.
//                Local Frobenius -> 1 atomic/block. SELF products symmetric
//                => tiles i<=j only, off-diag x2: 4*36+3*64=336 jobs.
// Frobenius structure => immune to any consistent K/row/col permutation and
// to MFMA operand/C/D layouts (A and B always loaded with the same scheme);
// x16 pre-scale folded into normalization, /16^4 at the end.

typedef __attribute__((ext_vector_type(4))) float floatx4;
typedef __attribute__((ext_vector_type(2))) long long llx2;
typedef __attribute__((ext_vector_type(8))) int intx8;

#define N_ROWS 4096
#define DDIM   512
// 100 / (4096^2 * 16^4)
#define LOSS_SCALE 9.094947017729282e-11f

__device__ __forceinline__ const float* sel_mod(int mod, const float* a,
                                                const float* b, const float* c,
                                                const float* d) {
  return mod == 0 ? a : mod == 1 ? b : mod == 2 ? c : d;
}

// bf16 RNE round-trip (keeps nT8 numerics identical to the bf16 pipeline)
__device__ __forceinline__ float bfr(float x) {
  __hip_bfloat16 h = __float2bfloat16(x);
  unsigned short u = *(unsigned short*)&h;
  return __uint_as_float(((unsigned int)u) << 16);
}

__global__ __launch_bounds__(512) void preprocess_kernel(
    const float* __restrict__ in0, const float* __restrict__ in1,
    const float* __restrict__ in2, const float* __restrict__ in3,
    unsigned char* __restrict__ nT8, float* __restrict__ out) {
  // grid: x = 64 (k-strips of 64 rows), y = 4 (mod). 512 threads = 8 waves.
  int mod = blockIdx.y;
  int k0 = blockIdx.x * 64;
  const float* X = sel_mod(mod, in0, in1, in2, in3) + (size_t)k0 * DDIM;

  if (blockIdx.x == 0 && blockIdx.y == 0 && threadIdx.x == 0)
    out[0] = 0.f;  // d_out re-poisoned each call; gram (next dispatch) accums

  __shared__ float rsc[64];
  // fp8-packed transpose tile: [512 cols][16 row-groups + 1 pad] words.
  // stride 17 (odd): pack-writes ~8 banks, phase-C b32 reads ~2-way (free).
  __shared__ unsigned int t8[512 * 17];  // 34.8 KB

  int t = threadIdx.x;
  int a = t >> 5;   // row-group 0..15 -> rows 4a..4a+3
  int bg = t & 31;  // col-group: float4 bg within each 128-col panel

  // single global read: 4 rows x 4 panels of float4 -> 64 VGPRs
  float4 v[4][4];  // [q][p]
#pragma unroll
  for (int q = 0; q < 4; ++q)
#pragma unroll
    for (int p = 0; p < 4; ++p)
      v[q][p] = ((const float4*)(X + (size_t)(4 * a + q) * DDIM + p * 128))[bg];

  // row-norm partials from registers; rows of group a live in one 32-lane
  // half-wave (t = a*32 + bg) -> width-32 shfl reduce
  float ss[4];
#pragma unroll
  for (int q = 0; q < 4; ++q) {
    float acc = 0.f;
#pragma unroll
    for (int p = 0; p < 4; ++p) {
      float4 u = v[q][p];
      acc += u.x * u.x + u.y * u.y + u.z * u.z + u.w * u.w;
    }
    ss[q] = acc;
  }
#pragma unroll
  for (int off = 16; off > 0; off >>= 1)
#pragma unroll
    for (int q = 0; q < 4; ++q) ss[q] += __shfl_down(ss[q], off, 32);
  if (bg == 0) {
#pragma unroll
    for (int q = 0; q < 4; ++q)
      rsc[4 * a + q] = 16.0f / fmaxf(sqrtf(ss[q]), 1e-12f);  // x16 folded
  }
  __syncthreads();

  float sc[4];
#pragma unroll
  for (int q = 0; q < 4; ++q) sc[q] = rsc[4 * a + q];

  // scale -> bf16 round -> fp8 pack (4 k-rows per word), straight from regs
#pragma unroll
  for (int p = 0; p < 4; ++p)
#pragma unroll
    for (int j = 0; j < 4; ++j) {
      float f0 = bfr(((const float*)&v[0][p])[j] * sc[0]);
      float f1 = bfr(((const float*)&v[1][p])[j] * sc[1]);
      float f2 = bfr(((const float*)&v[2][p])[j] * sc[2]);
      float f3 = bfr(((const float*)&v[3][p])[j] * sc[3]);
      unsigned int pk = __builtin_amdgcn_cvt_pk_fp8_f32(f0, f1, 0, 0);
      pk = __builtin_amdgcn_cvt_pk_fp8_f32(f2, f3, pk, 1);  // k-order bytes
      t8[(p * 128 + bg * 4 + j) * 17 + a] = pk;
    }
  __syncthreads();

  // output: 2048 x 16B; 4 adjacent lanes share a col -> 64B-contiguous runs
#pragma unroll
  for (int it = 0; it < 4; ++it) {
    int idx = it * 512 + t;
    int col = idx >> 2;  // 0..511
    int g = idx & 3;     // 16-byte k-group within the 64-row strip
    uint4 o;
    o.x = t8[col * 17 + g * 4 + 0];
    o.y = t8[col * 17 + g * 4 + 1];
    o.z = t8[col * 17 + g * 4 + 2];
    o.w = t8[col * 17 + g * 4 + 3];
    *(uint4*)(nT8 + ((size_t)(mod * DDIM + col)) * N_ROWS + k0 + g * 16) = o;
  }
}

__device__ __forceinline__ void stage_half(
    const unsigned char* __restrict__ base, int k0, unsigned char* ls,
    int lane) {
  // One wave stages one 64-row x 128B panel chunk (8 global_load_lds).
  // 16B-chunk XOR swizzle on the GLOBAL side: LDS slot s of local row r holds
  // global chunk s ^ ((r>>1)&7); LDS side is the wave-uniform base + lane*16
  // required by global_load_lds.
  int rr = lane >> 3;  // row 0..7 within the 8-row staging group
  int s = lane & 7;    // 16B slot within 128B row
#pragma unroll
  for (int c = 0; c < 8; ++c) {
    int row = c * 8 + rr;
    int gc = s ^ ((row >> 1) & 7);
    const unsigned char* g = base + (size_t)row * N_ROWS + k0 + gc * 16;
    __builtin_amdgcn_global_load_lds(
        (__attribute__((address_space(1))) void*)(void*)g,
        (__attribute__((address_space(3))) void*)(void*)&ls[c * 1024],
        16, 0, 0);
  }
}

__device__ __forceinline__ void compute_w(const unsigned char* ls,
                                          floatx4 acc[4][2], int wn, int lm,
                                          int lq) {
  // Lane (lm,lq): A rows mi*16+lm, B rows wn+ni*16+lm; 32 B of K per lane
  // (two b128 reads at unswizzled slots lq*2, lq*2+1) feed ONE K=128
  // mfma_scale per (mi,ni). Unit scales (E8M0 0x7F) => plain fp8 product.
  // Any operand-layout mismatch is a uniform row/col/K permutation applied
  // identically to A and B => Frobenius-invariant.
  intx8 A8[4], B8[2];
#pragma unroll
  for (int mi = 0; mi < 4; ++mi) {
    int row = mi * 16 + lm;  // local A row 0..63
    int sw = (row >> 1) & 7;
    *(llx2*)&A8[mi] = *(const llx2*)&ls[row * 128 + ((lq * 2) ^ sw) * 16];
    *((llx2*)&A8[mi] + 1) =
        *(const llx2*)&ls[row * 128 + ((lq * 2 + 1) ^ sw) * 16];
  }
#pragma unroll
  for (int ni = 0; ni < 2; ++ni) {
    int row = wn + ni * 16 + lm;  // local B row 0..63
    int sw = (row >> 1) & 7;
    *(llx2*)&B8[ni] =
        *(const llx2*)&ls[8192 + row * 128 + ((lq * 2) ^ sw) * 16];
    *((llx2*)&B8[ni] + 1) =
        *(const llx2*)&ls[8192 + row * 128 + ((lq * 2 + 1) ^ sw) * 16];
  }
  __builtin_amdgcn_s_setprio(1);
#pragma unroll
  for (int mi = 0; mi < 4; ++mi)
#pragma unroll
    for (int ni = 0; ni < 2; ++ni)
      acc[mi][ni] = __builtin_amdgcn_mfma_scale_f32_16x16x128_f8f6f4(
          A8[mi], B8[ni], acc[mi][ni], 0, 0,  // cbsz=0 (fp8), blgp=0 (fp8)
          0, 0x7F, 0, 0x7F);                  // opselA, scaleA, opselB, scaleB
  __builtin_amdgcn_s_setprio(0);
}

__global__ __launch_bounds__(128) void gram_frob_kernel(
    const unsigned char* __restrict__ nT8, float* __restrict__ out) {
  // 336 blocks x 2 waves. Job decode (after XCD swizzle):
  //   job <  144: self product (mods {t,r,d,i} with weights {3,1,1,1}),
  //               triangular tile i<=j of the 8x8 tile grid; off-diag x2.
  //   job >= 144: cross product (t,rgb)/(t,depth)/(t,ir), weight -2, 8x8.
  __shared__ __align__(16) unsigned char ls[4][16384];  // 4-deep, 64 KB
  __shared__ float red[2];

  // bijective XCD swizzle: 336 = 8 XCDs x 42 consecutive jobs
  int bx = blockIdx.x;
  int job = (bx & 7) * 42 + (bx >> 3);

  int pa_, pb_, ti, tj;
  float wgt;
  if (job < 144) {
    int p = job / 36;
    int t36 = job - p * 36;
    int i = 0;
    while (t36 >= 8 - i) { t36 -= 8 - i; ++i; }  // row i has 8-i entries
    ti = i;
    tj = i + t36;
    const int   sm[4] = {3, 0, 1, 2};
    const float sw_[4] = {3.f, 1.f, 1.f, 1.f};
    pa_ = sm[p];
    pb_ = sm[p];
    wgt = sw_[p] * (ti == tj ? 1.f : 2.f);
  } else {
    int r = job - 144;
    int p = r >> 6;  // 0..2 -> rgb, depth, ir
    int t64 = r & 63;
    ti = t64 >> 3;
    tj = t64 & 7;
    pa_ = 3;
    pb_ = p;
    wgt = -2.f;
  }

  const unsigned char* Abase = nT8 + ((size_t)pa_ * DDIM + ti * 64) * N_ROWS;
  const unsigned char* Bbase = nT8 + ((size_t)pb_ * DDIM + tj * 64) * N_ROWS;

  int t = threadIdx.x;
  int w = t >> 6;          // wave 0: stages A, computes N[0:32)
  int lane = t & 63;       // wave 1: stages B, computes N[32:64)
  int lm = lane & 15;
  int lq = lane >> 4;
  int wn = w * 32;
  const unsigned char* sbase = (w == 0) ? Abase : Bbase;
  int soff = w * 8192;

  floatx4 zero = {0.f, 0.f, 0.f, 0.f};
  floatx4 acc[4][2];
#pragma unroll
  for (int mi = 0; mi < 4; ++mi)
#pragma unroll
    for (int ni = 0; ni < 2; ++ni) acc[mi][ni] = zero;

  // 32 chunks of K=128. Per-wave counted vmcnt (8 own loads per chunk,
  // 3 chunks in flight = 24): wait own<=16 => own chunk-i loads landed;
  // raw s_barrier (no drain) publishes both halves.
  stage_half(sbase, 0, ls[0] + soff, lane);
  stage_half(sbase, 128, ls[1] + soff, lane);
  stage_half(sbase, 256, ls[2] + soff, lane);
  for (int i = 0; i < 29; ++i) {
    asm volatile("s_waitcnt vmcnt(16)" ::: "memory");
    __builtin_amdgcn_sched_barrier(0);
    __builtin_amdgcn_s_barrier();
    stage_half(sbase, (i + 3) * 128, ls[(i + 3) & 3] + soff, lane);
    compute_w(ls[i & 3], acc, wn, lm, lq);
  }
  asm volatile("s_waitcnt vmcnt(16)" ::: "memory");
  __builtin_amdgcn_sched_barrier(0);
  __builtin_amdgcn_s_barrier();
  compute_w(ls[1], acc, wn, lm, lq);  // chunk 29
  asm volatile("s_waitcnt vmcnt(8)" ::: "memory");
  __builtin_amdgcn_sched_barrier(0);
  __builtin_amdgcn_s_barrier();
  compute_w(ls[2], acc, wn, lm, lq);  // chunk 30
  asm volatile("s_waitcnt vmcnt(0)" ::: "memory");
  __builtin_amdgcn_sched_barrier(0);
  __builtin_amdgcn_s_barrier();
  compute_w(ls[3], acc, wn, lm, lq);  // chunk 31

  // Local Frobenius: C/D layout is a bijection -> sum of squares is exact.
  float s = 0.f;
#pragma unroll
  for (int mi = 0; mi < 4; ++mi)
#pragma unroll
    for (int ni = 0; ni < 2; ++ni)
#pragma unroll
      for (int r = 0; r < 4; ++r) {
        float v = acc[mi][ni][r];
        s += v * v;
      }
#pragma unroll
  for (int off = 32; off > 0; off >>= 1) s += __shfl_down(s, off, 64);
  if (lane == 0) red[w] = s;
  __syncthreads();
  if (t == 0)
    atomicAdd(out, wgt * LOSS_SCALE * (red[0] + red[1]));  // 336 atomics
}

extern "C" void kernel_launch(void* const* d_in, const int* in_sizes, int n_in,
                              void* d_out, int out_size, void* d_ws, size_t ws_size,
                              hipStream_t stream) {
  const float* in_rgb   = (const float*)d_in[0];
  const float* in_depth = (const float*)d_in[1];
  const float* in_ir    = (const float*)d_in[2];
  const float* in_t     = (const float*)d_in[3];

  unsigned char* nT8 = (unsigned char*)d_ws;  // 8 MB fp8, K-contiguous

  preprocess_kernel<<<dim3(64, 4), 512, 0, stream>>>(
      in_rgb, in_depth, in_ir, in_t, nT8, (float*)d_out);
  gram_frob_kernel<<<dim3(336), 128, 0, stream>>>(nT8, (float*)d_out);
}

// Round 4
// 101.772 us; speedup vs baseline: 1.1705x; 1.0336x over previous
//
#include <hip/hip_runtime.h>
#include <hip/hip_bf16.h>

// loss = (100/N^2) * [3*s_tt + s_rr + s_dd + s_ii - 2*(s_tr + s_td + s_ti)]
// where s_ab = || n_a^T n_b ||_F^2   (n_x = row-normalized input, N=4096, D=512)
//
// fp8 pipeline, 2 dispatches. nT8 layout is k-blocked:
//   nT8[ ((mod*64 + kb)*512 + c)*64 + dk ],  kb = k/64, dk = k%64  (8 MB)
// so K1 writes one contiguous 32 KB run per block and K2 stage loads cover
// two contiguous 512 B segments per instruction.
//
// K1 preprocess: SINGLE-READ fused rownorm + scale(16/||r||) + fp8 cast +
//                transpose; zeroes d_out. 64-row strips, 256 blocks (1/CU),
//                512 threads, register-resident 4x4 blocks.
// K2 gram:       TN-GEMMs 512x512 fp8 via MX-scaled
//                mfma_scale_f32_16x16x128_f8f6f4 with UNIT scales (0x7F) =
//                plain fp8 product at 2.3x the non-scaled fp8 rate. 336
//                blocks x 2 waves (N-split 64x32). PAIR-GROUPED XCD
//                schedule: all products of the same strip-pair {ti,tj} on
//                one XCD (8 panels = 2 MB <= 4 MB L2). 5-buffer LDS
//                (80 KB), 4-deep prefetch, per-wave counted vmcnt(24/16/8/0)
//                + raw s_barrier (no drain), XOR-swizzled stage + b128
//                conflict-free frag reads, local Frobenius -> 1 atomic/wave.
//                SELF products symmetric => tiles i<=j only, off-diag x2:
//                4*36 + 3*64 = 336 jobs.
// Frobenius structure => immune to any consistent K/row/col permutation and
// to MFMA operand/C/D layouts (A and B always loaded with the same scheme);
// x16 pre-scale folded into normalization, /16^4 at the end.

typedef __attribute__((ext_vector_type(4))) float floatx4;
typedef __attribute__((ext_vector_type(2))) long long llx2;
typedef __attribute__((ext_vector_type(8))) int intx8;

#define N_ROWS 4096
#define DDIM   512
// 100 / (4096^2 * 16^4)
#define LOSS_SCALE 9.094947017729282e-11f

__device__ __forceinline__ const float* sel_mod(int mod, const float* a,
                                                const float* b, const float* c,
                                                const float* d) {
  return mod == 0 ? a : mod == 1 ? b : mod == 2 ? c : d;
}

// bf16 RNE round-trip (keeps nT8 numerics identical to the bf16 pipeline)
__device__ __forceinline__ float bfr(float x) {
  __hip_bfloat16 h = __float2bfloat16(x);
  unsigned short u = *(unsigned short*)&h;
  return __uint_as_float(((unsigned int)u) << 16);
}

__global__ __launch_bounds__(512) void preprocess_kernel(
    const float* __restrict__ in0, const float* __restrict__ in1,
    const float* __restrict__ in2, const float* __restrict__ in3,
    unsigned char* __restrict__ nT8, float* __restrict__ out) {
  // grid: x = 64 (k-strips of 64 rows = one kb block), y = 4 (mod).
  int mod = blockIdx.y;
  int k0 = blockIdx.x * 64;
  const float* X = sel_mod(mod, in0, in1, in2, in3) + (size_t)k0 * DDIM;

  if (blockIdx.x == 0 && blockIdx.y == 0 && threadIdx.x == 0)
    out[0] = 0.f;  // d_out re-poisoned each call; gram (next dispatch) accums

  __shared__ float rsc[64];
  // fp8-packed transpose tile: [512 cols][16 row-groups + 1 pad] words.
  // stride 17 (odd): pack-writes ~8 banks, out-phase b32 reads ~2-way (free).
  __shared__ unsigned int t8[512 * 17];  // 34.8 KB

  int t = threadIdx.x;
  int a = t >> 5;   // row-group 0..15 -> rows 4a..4a+3
  int bg = t & 31;  // col-group: float4 bg within each 128-col panel

  // single global read: 4 rows x 4 panels of float4 -> 64 VGPRs
  float4 v[4][4];  // [q][p]
#pragma unroll
  for (int q = 0; q < 4; ++q)
#pragma unroll
    for (int p = 0; p < 4; ++p)
      v[q][p] = ((const float4*)(X + (size_t)(4 * a + q) * DDIM + p * 128))[bg];

  // row-norm partials from registers; rows of group a live in one 32-lane
  // half-wave (t = a*32 + bg) -> width-32 shfl reduce
  float ss[4];
#pragma unroll
  for (int q = 0; q < 4; ++q) {
    float acc = 0.f;
#pragma unroll
    for (int p = 0; p < 4; ++p) {
      float4 u = v[q][p];
      acc += u.x * u.x + u.y * u.y + u.z * u.z + u.w * u.w;
    }
    ss[q] = acc;
  }
#pragma unroll
  for (int off = 16; off > 0; off >>= 1)
#pragma unroll
    for (int q = 0; q < 4; ++q) ss[q] += __shfl_down(ss[q], off, 32);
  if (bg == 0) {
#pragma unroll
    for (int q = 0; q < 4; ++q)
      rsc[4 * a + q] = 16.0f / fmaxf(sqrtf(ss[q]), 1e-12f);  // x16 folded
  }
  __syncthreads();

  float sc[4];
#pragma unroll
  for (int q = 0; q < 4; ++q) sc[q] = rsc[4 * a + q];

  // scale -> bf16 round -> fp8 pack (4 k-rows per word), straight from regs
#pragma unroll
  for (int p = 0; p < 4; ++p)
#pragma unroll
    for (int j = 0; j < 4; ++j) {
      float f0 = bfr(((const float*)&v[0][p])[j] * sc[0]);
      float f1 = bfr(((const float*)&v[1][p])[j] * sc[1]);
      float f2 = bfr(((const float*)&v[2][p])[j] * sc[2]);
      float f3 = bfr(((const float*)&v[3][p])[j] * sc[3]);
      unsigned int pk = __builtin_amdgcn_cvt_pk_fp8_f32(f0, f1, 0, 0);
      pk = __builtin_amdgcn_cvt_pk_fp8_f32(f2, f3, pk, 1);  // k-order bytes
      t8[(p * 128 + bg * 4 + j) * 17 + a] = pk;
    }
  __syncthreads();

  // output: one contiguous 32 KB region per block (k-blocked layout):
  // flat byte off = c*64 + g*16 = idx*16
  size_t rbase = (size_t)(mod * 64 + blockIdx.x) * 32768;
#pragma unroll
  for (int it = 0; it < 4; ++it) {
    int idx = it * 512 + t;
    int col = idx >> 2;  // 0..511
    int g = idx & 3;     // 16-byte k-group within the 64-row strip
    uint4 o;
    o.x = t8[col * 17 + g * 4 + 0];
    o.y = t8[col * 17 + g * 4 + 1];
    o.z = t8[col * 17 + g * 4 + 2];
    o.w = t8[col * 17 + g * 4 + 3];
    *(uint4*)(nT8 + rbase + (size_t)idx * 16) = o;
  }
}

__device__ __forceinline__ void stage_half(
    const unsigned char* __restrict__ mbase, int cbase, int k0,
    unsigned char* ls, int lane) {
  // One wave stages one 64-col x K=128 panel chunk (8 global_load_lds).
  // k-blocked layout: 16B k-slot gc of col c sits at
  //   ((kb0 + (gc>>2))*512 + c)*64 + (gc&3)*16   (== k-offset gc*16).
  // 16B-chunk XOR swizzle on the GLOBAL side: LDS slot s of local row r
  // holds global k-slot s ^ ((r>>1)&7); LDS side is the wave-uniform base +
  // lane*16 required by global_load_lds.
  int rr = lane >> 3;  // row 0..7 within the 8-row staging group
  int s = lane & 7;    // 16B slot within the 128B k-run
  int kb0 = k0 >> 6;
#pragma unroll
  for (int c = 0; c < 8; ++c) {
    int row = c * 8 + rr;
    int gc = s ^ ((row >> 1) & 7);
    const unsigned char* g =
        mbase + ((size_t)(kb0 + (gc >> 2)) * 512 + cbase + row) * 64 +
        (gc & 3) * 16;
    __builtin_amdgcn_global_load_lds(
        (__attribute__((address_space(1))) void*)(void*)g,
        (__attribute__((address_space(3))) void*)(void*)&ls[c * 1024],
        16, 0, 0);
  }
}

__device__ __forceinline__ void compute_w(const unsigned char* ls,
                                          floatx4 acc[4][2], int wn, int lm,
                                          int lq) {
  // Lane (lm,lq): A rows mi*16+lm, B rows wn+ni*16+lm; 32 B of K per lane
  // (two b128 reads at unswizzled slots lq*2, lq*2+1) feed ONE K=128
  // mfma_scale per (mi,ni). Unit scales (E8M0 0x7F) => plain fp8 product.
  // Any operand-layout mismatch is a uniform row/col/K permutation applied
  // identically to A and B => Frobenius-invariant.
  intx8 A8[4], B8[2];
#pragma unroll
  for (int mi = 0; mi < 4; ++mi) {
    int row = mi * 16 + lm;  // local A row 0..63
    int sw = (row >> 1) & 7;
    *(llx2*)&A8[mi] = *(const llx2*)&ls[row * 128 + ((lq * 2) ^ sw) * 16];
    *((llx2*)&A8[mi] + 1) =
        *(const llx2*)&ls[row * 128 + ((lq * 2 + 1) ^ sw) * 16];
  }
#pragma unroll
  for (int ni = 0; ni < 2; ++ni) {
    int row = wn + ni * 16 + lm;  // local B row 0..63
    int sw = (row >> 1) & 7;
    *(llx2*)&B8[ni] =
        *(const llx2*)&ls[8192 + row * 128 + ((lq * 2) ^ sw) * 16];
    *((llx2*)&B8[ni] + 1) =
        *(const llx2*)&ls[8192 + row * 128 + ((lq * 2 + 1) ^ sw) * 16];
  }
  __builtin_amdgcn_s_setprio(1);
#pragma unroll
  for (int mi = 0; mi < 4; ++mi)
#pragma unroll
    for (int ni = 0; ni < 2; ++ni)
      acc[mi][ni] = __builtin_amdgcn_mfma_scale_f32_16x16x128_f8f6f4(
          A8[mi], B8[ni], acc[mi][ni], 0, 0,  // cbsz=0 (fp8), blgp=0 (fp8)
          0, 0x7F, 0, 0x7F);                  // opselA, scaleA, opselB, scaleB
  __builtin_amdgcn_s_setprio(0);
}

__global__ __launch_bounds__(128) void gram_frob_kernel(
    const unsigned char* __restrict__ nT8, float* __restrict__ out) {
  // 336 blocks x 2 waves, PAIR-GROUPED: jobs enumerated group-major over
  // unordered strip pairs {ti,tj} (diag groups: 4 self + 3 cross = 7 jobs;
  // off-diag: 4 self(x2) + 3 cross x 2 orientations = 10 jobs). XCD swizzle
  // (bx&7)*42 + bx>>3 puts each group's jobs on one XCD => its 8 panels
  // (2 MB) stay L2-resident.
  __shared__ __align__(16) unsigned char ls[5][16384];  // 5-deep, 80 KB

  int bx = blockIdx.x;
  int job = (bx & 7) * 42 + (bx >> 3);

  // decode job -> (ti, tj, idx-within-group)
  int rem = job, ti = 7, tj = 7;
  for (int i = 0; i < 8; ++i) {
    int rowlen = 7 + 10 * (7 - i);  // diag group + (7-i) off-diag groups
    if (rem < rowlen) {
      if (rem < 7) {
        ti = i; tj = i;
      } else {
        int r2 = rem - 7;
        ti = i; tj = i + 1 + r2 / 10;
        rem = r2 % 10;
      }
      break;
    }
    rem -= rowlen;
  }

  int pa_, pb_, a0, b0;
  float wgt;
  if (ti == tj) {
    if (rem < 4) { pa_ = pb_ = rem; wgt = (rem == 3) ? 3.f : 1.f; }
    else         { pa_ = 3; pb_ = rem - 4; wgt = -2.f; }
    a0 = ti * 64; b0 = ti * 64;
  } else {
    if (rem < 4) {
      pa_ = pb_ = rem; wgt = (rem == 3) ? 6.f : 2.f;  // off-diag self x2
      a0 = ti * 64; b0 = tj * 64;
    } else {
      int k = rem - 4;
      pa_ = 3; pb_ = k >> 1; wgt = -2.f;
      if (k & 1) { a0 = tj * 64; b0 = ti * 64; }
      else       { a0 = ti * 64; b0 = tj * 64; }
    }
  }

  const unsigned char* Abase = nT8 + (size_t)pa_ * 2097152;  // 2 MB per mod
  const unsigned char* Bbase = nT8 + (size_t)pb_ * 2097152;

  int t = threadIdx.x;
  int w = t >> 6;     // wave 0: stages A, computes N[0:32)
  int lane = t & 63;  // wave 1: stages B, computes N[32:64)
  int lm = lane & 15;
  int lq = lane >> 4;
  int wn = w * 32;
  const unsigned char* mbase = (w == 0) ? Abase : Bbase;
  int cb = (w == 0) ? a0 : b0;
  int soff = w * 8192;

  floatx4 zero = {0.f, 0.f, 0.f, 0.f};
  floatx4 acc[4][2];
#pragma unroll
  for (int mi = 0; mi < 4; ++mi)
#pragma unroll
    for (int ni = 0; ni < 2; ++ni) acc[mi][ni] = zero;

  // 32 chunks of K=128, 5 buffers, 4-deep prefetch. Per-wave counted vmcnt
  // (8 own loads per stage, 4 chunks in flight = 32): wait own<=24 => own
  // chunk-i loads landed; raw s_barrier (no drain) publishes both halves.
  unsigned char* p0 = ls[0] + soff;
  unsigned char* p1 = ls[1] + soff;
  unsigned char* p2 = ls[2] + soff;
  unsigned char* p3 = ls[3] + soff;
  unsigned char* p4 = ls[4] + soff;
  stage_half(mbase, cb, 0, p0, lane);
  stage_half(mbase, cb, 128, p1, lane);
  stage_half(mbase, cb, 256, p2, lane);
  stage_half(mbase, cb, 384, p3, lane);
  for (int i = 0; i < 28; ++i) {
    asm volatile("s_waitcnt vmcnt(24)" ::: "memory");
    __builtin_amdgcn_sched_barrier(0);
    __builtin_amdgcn_s_barrier();
    stage_half(mbase, cb, (i + 4) * 128, p4, lane);
    compute_w(p0 - soff, acc, wn, lm, lq);
    unsigned char* tmp = p0; p0 = p1; p1 = p2; p2 = p3; p3 = p4; p4 = tmp;
  }
  asm volatile("s_waitcnt vmcnt(24)" ::: "memory");
  __builtin_amdgcn_sched_barrier(0);
  __builtin_amdgcn_s_barrier();
  compute_w(p0 - soff, acc, wn, lm, lq);  // chunk 28
  asm volatile("s_waitcnt vmcnt(16)" ::: "memory");
  __builtin_amdgcn_sched_barrier(0);
  __builtin_amdgcn_s_barrier();
  compute_w(p1 - soff, acc, wn, lm, lq);  // chunk 29
  asm volatile("s_waitcnt vmcnt(8)" ::: "memory");
  __builtin_amdgcn_sched_barrier(0);
  __builtin_amdgcn_s_barrier();
  compute_w(p2 - soff, acc, wn, lm, lq);  // chunk 30
  asm volatile("s_waitcnt vmcnt(0)" ::: "memory");
  __builtin_amdgcn_sched_barrier(0);
  __builtin_amdgcn_s_barrier();
  compute_w(p3 - soff, acc, wn, lm, lq);  // chunk 31

  // Local Frobenius: C/D layout is a bijection -> sum of squares is exact.
  float s = 0.f;
#pragma unroll
  for (int mi = 0; mi < 4; ++mi)
#pragma unroll
    for (int ni = 0; ni < 2; ++ni)
#pragma unroll
      for (int r = 0; r < 4; ++r) {
        float v = acc[mi][ni][r];
        s += v * v;
      }
#pragma unroll
  for (int off = 32; off > 0; off >>= 1) s += __shfl_down(s, off, 64);
  if (lane == 0)
    atomicAdd(out, wgt * LOSS_SCALE * s);  // 672 atomics total
}

extern "C" void kernel_launch(void* const* d_in, const int* in_sizes, int n_in,
                              void* d_out, int out_size, void* d_ws, size_t ws_size,
                              hipStream_t stream) {
  const float* in_rgb   = (const float*)d_in[0];
  const float* in_depth = (const float*)d_in[1];
  const float* in_ir    = (const float*)d_in[2];
  const float* in_t     = (const float*)d_in[3];

  unsigned char* nT8 = (unsigned char*)d_ws;  // 8 MB fp8, k-blocked layout

  preprocess_kernel<<<dim3(64, 4), 512, 0, stream>>>(
      in_rgb, in_depth, in_ir, in_t, nT8, (float*)d_out);
  gram_frob_kernel<<<dim3(336), 128, 0, stream>>>(nT8, (float*)d_out);
}

// Round 5
// 101.730 us; speedup vs baseline: 1.1710x; 1.0004x over previous
//
#include <hip/hip_runtime.h>
#include <hip/hip_bf16.h>

// loss = (100/N^2) * [3*s_tt + s_rr + s_dd + s_ii - 2*(s_tr + s_td + s_ti)]
// where s_ab = || n_a^T n_b ||_F^2   (n_x = row-normalized input, N=4096, D=512)
//
// fp8 pipeline, 2 dispatches. nT8 layout is k-blocked:
//   nT8[ ((mod*64 + kb)*512 + c)*64 + dk ],  kb = k/64, dk = k%64  (8 MB)
// so K1 writes one contiguous 32 KB run per block and K2 stage loads cover
// two contiguous 512 B segments per instruction.
//
// K1 preprocess: SINGLE-READ fused rownorm + scale(16/||r||) + fp8 cast +
//                transpose; zeroes d_out. 64-row strips, 256 blocks (1/CU),
//                512 threads, register-resident 4x4 blocks.
// K2 gram:       TN-GEMMs 512x512 fp8 via MX-scaled
//                mfma_scale_f32_16x16x128_f8f6f4 with UNIT scales (0x7F) =
//                plain fp8 product at 2.3x the non-scaled fp8 rate. 336
//                blocks x 2 waves (N-split 64x32), pair-grouped XCD
//                schedule, 5-buffer LDS (80 KB), 4-deep prefetch.
//                CRITICAL: fragment loads are inline-asm ds_read_b128 on
//                as3 pointers (no memory clobber) -- keeps LLVM's waitcnt
//                pass from seeing LDS reads that alias the LDS-DMA and
//                inserting its own s_waitcnt vmcnt(0) per chunk (which
//                collapses the prefetch pipeline to depth-0). The ONLY
//                in-loop waits are hand-counted vmcnt(24/16/8/0) +
//                lgkmcnt(0) before the MFMA cluster (+ sched_barrier, rule
//                "asm ds_read needs sched_barrier after lgkmcnt").
//                Local Frobenius -> 1 atomic/wave. SELF products symmetric
//                => tiles i<=j only, off-diag x2: 4*36 + 3*64 = 336 jobs.
// Frobenius structure => immune to any consistent K/row/col permutation and
// to MFMA operand/C/D layouts (A and B always loaded with the same scheme);
// x16 pre-scale folded into normalization, /16^4 at the end.

typedef __attribute__((ext_vector_type(4))) float floatx4;
typedef __attribute__((ext_vector_type(2))) long long llx2;
typedef __attribute__((ext_vector_type(8))) int intx8;

typedef __attribute__((address_space(3))) unsigned char* lds_u8p;
typedef const __attribute__((address_space(3))) unsigned char* lds_cu8p;

#define N_ROWS 4096
#define DDIM   512
// 100 / (4096^2 * 16^4)
#define LOSS_SCALE 9.094947017729282e-11f

__device__ __forceinline__ const float* sel_mod(int mod, const float* a,
                                                const float* b, const float* c,
                                                const float* d) {
  return mod == 0 ? a : mod == 1 ? b : mod == 2 ? c : d;
}

// bf16 RNE round-trip (keeps nT8 numerics identical to the bf16 pipeline)
__device__ __forceinline__ float bfr(float x) {
  __hip_bfloat16 h = __float2bfloat16(x);
  unsigned short u = *(unsigned short*)&h;
  return __uint_as_float(((unsigned int)u) << 16);
}

// Opaque LDS read: compiler's waitcnt pass sees a register-only asm and
// inserts no vmcnt/lgkmcnt around it; WE wait with lgkmcnt(0) before use.
__device__ __forceinline__ llx2 ldsr16(lds_cu8p p) {
  llx2 r;
  asm volatile("ds_read_b128 %0, %1" : "=v"(r) : "v"(p));
  return r;
}

__global__ __launch_bounds__(512) void preprocess_kernel(
    const float* __restrict__ in0, const float* __restrict__ in1,
    const float* __restrict__ in2, const float* __restrict__ in3,
    unsigned char* __restrict__ nT8, float* __restrict__ out) {
  // grid: x = 64 (k-strips of 64 rows = one kb block), y = 4 (mod).
  int mod = blockIdx.y;
  int k0 = blockIdx.x * 64;
  const float* X = sel_mod(mod, in0, in1, in2, in3) + (size_t)k0 * DDIM;

  if (blockIdx.x == 0 && blockIdx.y == 0 && threadIdx.x == 0)
    out[0] = 0.f;  // d_out re-poisoned each call; gram (next dispatch) accums

  __shared__ float rsc[64];
  // fp8-packed transpose tile: [512 cols][16 row-groups + 1 pad] words.
  // stride 17 (odd): pack-writes ~8 banks, out-phase b32 reads ~2-way (free).
  __shared__ unsigned int t8[512 * 17];  // 34.8 KB

  int t = threadIdx.x;
  int a = t >> 5;   // row-group 0..15 -> rows 4a..4a+3
  int bg = t & 31;  // col-group: float4 bg within each 128-col panel

  // single global read: 4 rows x 4 panels of float4 -> 64 VGPRs
  float4 v[4][4];  // [q][p]
#pragma unroll
  for (int q = 0; q < 4; ++q)
#pragma unroll
    for (int p = 0; p < 4; ++p)
      v[q][p] = ((const float4*)(X + (size_t)(4 * a + q) * DDIM + p * 128))[bg];

  // row-norm partials from registers; rows of group a live in one 32-lane
  // half-wave (t = a*32 + bg) -> width-32 shfl reduce
  float ss[4];
#pragma unroll
  for (int q = 0; q < 4; ++q) {
    float acc = 0.f;
#pragma unroll
    for (int p = 0; p < 4; ++p) {
      float4 u = v[q][p];
      acc += u.x * u.x + u.y * u.y + u.z * u.z + u.w * u.w;
    }
    ss[q] = acc;
  }
#pragma unroll
  for (int off = 16; off > 0; off >>= 1)
#pragma unroll
    for (int q = 0; q < 4; ++q) ss[q] += __shfl_down(ss[q], off, 32);
  if (bg == 0) {
#pragma unroll
    for (int q = 0; q < 4; ++q)
      rsc[4 * a + q] = 16.0f / fmaxf(sqrtf(ss[q]), 1e-12f);  // x16 folded
  }
  __syncthreads();

  float sc[4];
#pragma unroll
  for (int q = 0; q < 4; ++q) sc[q] = rsc[4 * a + q];

  // scale -> bf16 round -> fp8 pack (4 k-rows per word), straight from regs
#pragma unroll
  for (int p = 0; p < 4; ++p)
#pragma unroll
    for (int j = 0; j < 4; ++j) {
      float f0 = bfr(((const float*)&v[0][p])[j] * sc[0]);
      float f1 = bfr(((const float*)&v[1][p])[j] * sc[1]);
      float f2 = bfr(((const float*)&v[2][p])[j] * sc[2]);
      float f3 = bfr(((const float*)&v[3][p])[j] * sc[3]);
      unsigned int pk = __builtin_amdgcn_cvt_pk_fp8_f32(f0, f1, 0, 0);
      pk = __builtin_amdgcn_cvt_pk_fp8_f32(f2, f3, pk, 1);  // k-order bytes
      t8[(p * 128 + bg * 4 + j) * 17 + a] = pk;
    }
  __syncthreads();

  // output: one contiguous 32 KB region per block (k-blocked layout):
  // flat byte off = c*64 + g*16 = idx*16
  size_t rbase = (size_t)(mod * 64 + blockIdx.x) * 32768;
#pragma unroll
  for (int it = 0; it < 4; ++it) {
    int idx = it * 512 + t;
    int col = idx >> 2;  // 0..511
    int g = idx & 3;     // 16-byte k-group within the 64-row strip
    uint4 o;
    o.x = t8[col * 17 + g * 4 + 0];
    o.y = t8[col * 17 + g * 4 + 1];
    o.z = t8[col * 17 + g * 4 + 2];
    o.w = t8[col * 17 + g * 4 + 3];
    *(uint4*)(nT8 + rbase + (size_t)idx * 16) = o;
  }
}

__device__ __forceinline__ void stage_half(
    const unsigned char* __restrict__ mbase, int cbase, int k0,
    lds_u8p dst, int lane) {
  // One wave stages one 64-col x K=128 panel chunk (8 global_load_lds).
  // k-blocked layout: 16B k-slot gc of col c sits at
  //   ((kb0 + (gc>>2))*512 + c)*64 + (gc&3)*16   (== k-offset gc*16).
  // 16B-chunk XOR swizzle on the GLOBAL side: LDS slot s of local row r
  // holds global k-slot s ^ ((r>>1)&7); LDS side is the wave-uniform base +
  // lane*16 required by global_load_lds.
  int rr = lane >> 3;  // row 0..7 within the 8-row staging group
  int s = lane & 7;    // 16B slot within the 128B k-run
  int kb0 = k0 >> 6;
#pragma unroll
  for (int c = 0; c < 8; ++c) {
    int row = c * 8 + rr;
    int gc = s ^ ((row >> 1) & 7);
    const unsigned char* g =
        mbase + ((size_t)(kb0 + (gc >> 2)) * 512 + cbase + row) * 64 +
        (gc & 3) * 16;
    __builtin_amdgcn_global_load_lds(
        (__attribute__((address_space(1))) void*)(void*)g,
        (__attribute__((address_space(3))) void*)(dst + c * 1024),
        16, 0, 0);
  }
}

__device__ __forceinline__ void compute_w(lds_cu8p lsb, floatx4 acc[4][2],
                                          int wn, int lm, int lq) {
  // Lane (lm,lq): A rows mi*16+lm, B rows wn+ni*16+lm; 32 B of K per lane
  // (two asm ds_read_b128 at unswizzled slots lq*2, lq*2+1) feed ONE K=128
  // mfma_scale per (mi,ni). Unit scales (E8M0 0x7F) => plain fp8 product.
  // Any operand-layout mismatch is a uniform row/col/K permutation applied
  // identically to A and B => Frobenius-invariant.
  intx8 A8[4], B8[2];
#pragma unroll
  for (int mi = 0; mi < 4; ++mi) {
    int row = mi * 16 + lm;  // local A row 0..63
    int sw = (row >> 1) & 7;
    *(llx2*)&A8[mi] = ldsr16(lsb + row * 128 + ((lq * 2) ^ sw) * 16);
    *((llx2*)&A8[mi] + 1) =
        ldsr16(lsb + row * 128 + ((lq * 2 + 1) ^ sw) * 16);
  }
#pragma unroll
  for (int ni = 0; ni < 2; ++ni) {
    int row = wn + ni * 16 + lm;  // local B row 0..63
    int sw = (row >> 1) & 7;
    *(llx2*)&B8[ni] =
        ldsr16(lsb + 8192 + row * 128 + ((lq * 2) ^ sw) * 16);
    *((llx2*)&B8[ni] + 1) =
        ldsr16(lsb + 8192 + row * 128 + ((lq * 2 + 1) ^ sw) * 16);
  }
  // ds_read results are NOT scoreboarded: wait, then fence the scheduler so
  // the MFMAs cannot be hoisted above the wait (rule #18).
  asm volatile("s_waitcnt lgkmcnt(0)");
  __builtin_amdgcn_sched_barrier(0);
  __builtin_amdgcn_s_setprio(1);
#pragma unroll
  for (int mi = 0; mi < 4; ++mi)
#pragma unroll
    for (int ni = 0; ni < 2; ++ni)
      acc[mi][ni] = __builtin_amdgcn_mfma_scale_f32_16x16x128_f8f6f4(
          A8[mi], B8[ni], acc[mi][ni], 0, 0,  // cbsz=0 (fp8), blgp=0 (fp8)
          0, 0x7F, 0, 0x7F);                  // opselA, scaleA, opselB, scaleB
  __builtin_amdgcn_s_setprio(0);
}

__global__ __launch_bounds__(128) void gram_frob_kernel(
    const unsigned char* __restrict__ nT8, float* __restrict__ out) {
  // 336 blocks x 2 waves, PAIR-GROUPED: jobs enumerated group-major over
  // unordered strip pairs {ti,tj} (diag groups: 4 self + 3 cross = 7 jobs;
  // off-diag: 4 self(x2) + 3 cross x 2 orientations = 10 jobs). XCD swizzle
  // (bx&7)*42 + bx>>3 puts each group's jobs on one XCD => its panels stay
  // L2-resident.
  __shared__ __align__(16) unsigned char ls[5][16384];  // 5-deep, 80 KB

  int bx = blockIdx.x;
  int job = (bx & 7) * 42 + (bx >> 3);

  // decode job -> (ti, tj, idx-within-group)
  int rem = job, ti = 7, tj = 7;
  for (int i = 0; i < 8; ++i) {
    int rowlen = 7 + 10 * (7 - i);  // diag group + (7-i) off-diag groups
    if (rem < rowlen) {
      if (rem < 7) {
        ti = i; tj = i;
      } else {
        int r2 = rem - 7;
        ti = i; tj = i + 1 + r2 / 10;
        rem = r2 % 10;
      }
      break;
    }
    rem -= rowlen;
  }

  int pa_, pb_, a0, b0;
  float wgt;
  if (ti == tj) {
    if (rem < 4) { pa_ = pb_ = rem; wgt = (rem == 3) ? 3.f : 1.f; }
    else         { pa_ = 3; pb_ = rem - 4; wgt = -2.f; }
    a0 = ti * 64; b0 = ti * 64;
  } else {
    if (rem < 4) {
      pa_ = pb_ = rem; wgt = (rem == 3) ? 6.f : 2.f;  // off-diag self x2
      a0 = ti * 64; b0 = tj * 64;
    } else {
      int k = rem - 4;
      pa_ = 3; pb_ = k >> 1; wgt = -2.f;
      if (k & 1) { a0 = tj * 64; b0 = ti * 64; }
      else       { a0 = ti * 64; b0 = tj * 64; }
    }
  }

  const unsigned char* Abase = nT8 + (size_t)pa_ * 2097152;  // 2 MB per mod
  const unsigned char* Bbase = nT8 + (size_t)pb_ * 2097152;

  int t = threadIdx.x;
  int w = t >> 6;     // wave 0: stages A, computes N[0:32)
  int lane = t & 63;  // wave 1: stages B, computes N[32:64)
  int lm = lane & 15;
  int lq = lane >> 4;
  int wn = w * 32;
  const unsigned char* mbase = (w == 0) ? Abase : Bbase;
  int cb = (w == 0) ? a0 : b0;
  int soff = w * 8192;

  floatx4 zero = {0.f, 0.f, 0.f, 0.f};
  floatx4 acc[4][2];
#pragma unroll
  for (int mi = 0; mi < 4; ++mi)
#pragma unroll
    for (int ni = 0; ni < 2; ++ni) acc[mi][ni] = zero;

  // 32 chunks of K=128, 5 buffers, 4-deep prefetch. Per-wave counted vmcnt
  // (8 own loads per stage, 4 chunks in flight = 32): wait own<=24 => own
  // chunk-i loads landed; raw s_barrier (no drain) publishes both halves.
  lds_u8p lbase = (lds_u8p)(void*)&ls[0][0];
  lds_u8p p0 = lbase + 0 * 16384 + soff;
  lds_u8p p1 = lbase + 1 * 16384 + soff;
  lds_u8p p2 = lbase + 2 * 16384 + soff;
  lds_u8p p3 = lbase + 3 * 16384 + soff;
  lds_u8p p4 = lbase + 4 * 16384 + soff;
  stage_half(mbase, cb, 0, p0, lane);
  stage_half(mbase, cb, 128, p1, lane);
  stage_half(mbase, cb, 256, p2, lane);
  stage_half(mbase, cb, 384, p3, lane);
  for (int i = 0; i < 28; ++i) {
    asm volatile("s_waitcnt vmcnt(24)");
    __builtin_amdgcn_sched_barrier(0);
    __builtin_amdgcn_s_barrier();
    stage_half(mbase, cb, (i + 4) * 128, p4, lane);
    compute_w((lds_cu8p)(p0 - soff), acc, wn, lm, lq);
    lds_u8p tmp = p0; p0 = p1; p1 = p2; p2 = p3; p3 = p4; p4 = tmp;
  }
  asm volatile("s_waitcnt vmcnt(24)");
  __builtin_amdgcn_sched_barrier(0);
  __builtin_amdgcn_s_barrier();
  compute_w((lds_cu8p)(p0 - soff), acc, wn, lm, lq);  // chunk 28
  asm volatile("s_waitcnt vmcnt(16)");
  __builtin_amdgcn_sched_barrier(0);
  __builtin_amdgcn_s_barrier();
  compute_w((lds_cu8p)(p1 - soff), acc, wn, lm, lq);  // chunk 29
  asm volatile("s_waitcnt vmcnt(8)");
  __builtin_amdgcn_sched_barrier(0);
  __builtin_amdgcn_s_barrier();
  compute_w((lds_cu8p)(p2 - soff), acc, wn, lm, lq);  // chunk 30
  asm volatile("s_waitcnt vmcnt(0)");
  __builtin_amdgcn_sched_barrier(0);
  __builtin_amdgcn_s_barrier();
  compute_w((lds_cu8p)(p3 - soff), acc, wn, lm, lq);  // chunk 31

  // Local Frobenius: C/D layout is a bijection -> sum of squares is exact.
  float s = 0.f;
#pragma unroll
  for (int mi = 0; mi < 4; ++mi)
#pragma unroll
    for (int ni = 0; ni < 2; ++ni)
#pragma unroll
      for (int r = 0; r < 4; ++r) {
        float v = acc[mi][ni][r];
        s += v * v;
      }
#pragma unroll
  for (int off = 32; off > 0; off >>= 1) s += __shfl_down(s, off, 64);
  if (lane == 0)
    atomicAdd(out, wgt * LOSS_SCALE * s);  // 672 atomics total
}

extern "C" void kernel_launch(void* const* d_in, const int* in_sizes, int n_in,
                              void* d_out, int out_size, void* d_ws, size_t ws_size,
                              hipStream_t stream) {
  const float* in_rgb   = (const float*)d_in[0];
  const float* in_depth = (const float*)d_in[1];
  const float* in_ir    = (const float*)d_in[2];
  const float* in_t     = (const float*)d_in[3];

  unsigned char* nT8 = (unsigned char*)d_ws;  // 8 MB fp8, k-blocked layout

  preprocess_kernel<<<dim3(64, 4), 512, 0, stream>>>(
      in_rgb, in_depth, in_ir, in_t, nT8, (float*)d_out);
  gram_frob_kernel<<<dim3(336), 128, 0, stream>>>(nT8, (float*)d_out);
}